// Round 8
// baseline (184.835 us; speedup 1.0000x reference)
//
#include <hip/hip_runtime.h>
#include <hip/hip_bf16.h>
#include <cstdint>

#define BATCH 4
#define SEQ   2048
#define DIN   1024
#define DOUT  1024
#define SCALE 0.03125f   // 1/sqrt(1024)

typedef unsigned short u16;
typedef float  f32x4  __attribute__((ext_vector_type(4)));
typedef __bf16 bf16x8 __attribute__((ext_vector_type(8)));

__device__ __forceinline__ u16 f2bf(float f) {
    unsigned u = __float_as_uint(f);
    unsigned r = 0x7fffu + ((u >> 16) & 1u);
    return (u16)((u + r) >> 16);
}

__device__ __forceinline__ f32x4 mfma16(bf16x8 a, bf16x8 b, f32x4 c) {
    return __builtin_amdgcn_mfma_f32_16x16x32_bf16(a, b, c, 0, 0, 0);
}

__device__ __forceinline__ void gl_lds16(const u16* g, u16* l) {
    __builtin_amdgcn_global_load_lds(
        (const __attribute__((address_space(1))) unsigned int*)g,
        (__attribute__((address_space(3))) unsigned int*)l, 16, 0, 0);
}

#define BAR    asm volatile("s_barrier" ::: "memory")
#define VMCNT4 asm volatile("s_waitcnt vmcnt(4)" ::: "memory")
#define VMCNT0 asm volatile("s_waitcnt vmcnt(0)" ::: "memory")
#define LGKM0  asm volatile("s_waitcnt lgkmcnt(0)" ::: "memory")

// ---------------- fused fp32 -> bf16 conversion (x | wq | wk | wv) ---------
__global__ __launch_bounds__(256) void cvt_all(const float* __restrict__ x,
                                               const float* __restrict__ wq,
                                               const float* __restrict__ wk,
                                               const float* __restrict__ wv,
                                               u16* __restrict__ dst) {
    const size_t NX = (size_t)BATCH * SEQ * DIN;
    size_t e = ((size_t)blockIdx.x * 256 + threadIdx.x) * 8;
    const float* src;
    size_t off;
    if (e < NX) { src = x; off = e; }
    else {
        size_t r = e - NX;
        int w = (int)(r >> 20);
        src = (w == 0) ? wq : (w == 1) ? wk : wv;
        off = r & ((1u << 20) - 1);
    }
    f32x4 a = *(const f32x4*)(src + off);
    f32x4 b = *(const f32x4*)(src + off + 4);
    uint4 o;
    o.x = (unsigned)f2bf(a[0]) | ((unsigned)f2bf(a[1]) << 16);
    o.y = (unsigned)f2bf(a[2]) | ((unsigned)f2bf(a[3]) << 16);
    o.z = (unsigned)f2bf(b[0]) | ((unsigned)f2bf(b[1]) << 16);
    o.w = (unsigned)f2bf(b[2]) | ((unsigned)f2bf(b[3]) << 16);
    *(uint4*)(dst + e) = o;
}

// ======================================================================
// Staging: 128-row x 64-col bf16 unit (16KB), linear rows, row-XOR
// swizzle (byte ^= (row&7)<<4) applied inverse on the global source.
// Each thread always writes its own fixed LDS slice (race-free reuse).
// ======================================================================
__device__ __forceinline__ void stg128(const u16* __restrict__ g, int ld,
                                       u16* unit, int tid) {
#pragma unroll
    for (int i = 0; i < 2; i++) {
        int D = (i * 512 + tid) * 16;
        int r = D >> 7, w = D & 127;
        int gcol = (w ^ ((r & 7) << 4)) >> 1;
        gl_lds16(g + (size_t)r * ld + gcol, unit + (i * 512 + (tid >> 6) * 64) * 8);
    }
}

__device__ __forceinline__ void rd4(const u16* unit, int rowbase, int l15, int l4,
                                    bf16x8 f[4][2]) {
    const char* u = (const char*)unit;
#pragma unroll
    for (int i = 0; i < 4; i++) {
        int row = rowbase + i * 16 + l15;
#pragma unroll
        for (int kk = 0; kk < 2; kk++)
            f[i][kk] = *(const bf16x8*)(u + row * 128 +
                                        ((kk * 64 + l4 * 16) ^ ((row & 7) << 4)));
    }
}

__device__ __forceinline__ void rd2k(const u16* unit, int row0, int l15, int l4,
                                     bf16x8 f[2]) {
    const char* u = (const char*)unit;
    int row = row0 + l15;
#pragma unroll
    for (int kk = 0; kk < 2; kk++)
        f[kk] = *(const bf16x8*)(u + row * 128 +
                                 ((kk * 64 + l4 * 16) ^ ((row & 7) << 4)));
}

// ======================================================================
// G64: 128x128 tile, BK=64, 8 waves (2M x 4N), per-wave 64x32, 64KB LDS
// -> 2 blocks/CU. 2-phase K-step: ph1 {12 ds_read | BAR | 8 MFMA | lgkm0
// | BAR}; ph2 {stage t+2 (4 gl_lds) | vmcnt(4) | BAR | 8 MFMA | BAR}.
// ======================================================================
__device__ __forceinline__ void g64_body(u16* lds, const u16* __restrict__ Ag,
                                         int lda, const u16* __restrict__ Bg,
                                         int ldb, int nkt, int wm, int wn,
                                         int l15, int l4, int tid,
                                         f32x4 acc[4][2]) {
    bf16x8 a[4][2], b0[2], b1[2];
    u16* A0 = lds;          u16* B0 = lds + 8192;
    u16* A1 = lds + 16384;  u16* B1 = lds + 24576;
    stg128(Ag, lda, A0, tid);      stg128(Bg, ldb, B0, tid);
    stg128(Ag + 64, lda, A1, tid); stg128(Bg + 64, ldb, B1, tid);
    VMCNT4; BAR;
    for (int t = 0; t < nkt; t += 2) {
        {
            const int k2 = ((t + 2 < nkt) ? t + 2 : nkt - 1) * 64;
            rd4(A0, wm * 64, l15, l4, a);
            rd2k(B0, wn * 32, l15, l4, b0);
            rd2k(B0, wn * 32 + 16, l15, l4, b1);
            BAR;
            __builtin_amdgcn_s_setprio(1);
#pragma unroll
            for (int kk = 0; kk < 2; kk++)
#pragma unroll
                for (int mi = 0; mi < 4; mi++)
                    acc[mi][0] = mfma16(a[mi][kk], b0[kk], acc[mi][0]);
            __builtin_amdgcn_s_setprio(0);
            LGKM0; BAR;
            stg128(Ag + k2, lda, A0, tid);
            stg128(Bg + k2, ldb, B0, tid);
            VMCNT4; BAR;
            __builtin_amdgcn_s_setprio(1);
#pragma unroll
            for (int kk = 0; kk < 2; kk++)
#pragma unroll
                for (int mi = 0; mi < 4; mi++)
                    acc[mi][1] = mfma16(a[mi][kk], b1[kk], acc[mi][1]);
            __builtin_amdgcn_s_setprio(0);
            BAR;
        }
        {
            const int k3 = ((t + 3 < nkt) ? t + 3 : nkt - 1) * 64;
            rd4(A1, wm * 64, l15, l4, a);
            rd2k(B1, wn * 32, l15, l4, b0);
            rd2k(B1, wn * 32 + 16, l15, l4, b1);
            BAR;
            __builtin_amdgcn_s_setprio(1);
#pragma unroll
            for (int kk = 0; kk < 2; kk++)
#pragma unroll
                for (int mi = 0; mi < 4; mi++)
                    acc[mi][0] = mfma16(a[mi][kk], b0[kk], acc[mi][0]);
            __builtin_amdgcn_s_setprio(0);
            LGKM0; BAR;
            stg128(Ag + k3, lda, A1, tid);
            stg128(Bg + k3, ldb, B1, tid);
            VMCNT4; BAR;
            __builtin_amdgcn_s_setprio(1);
#pragma unroll
            for (int kk = 0; kk < 2; kk++)
#pragma unroll
                for (int mi = 0; mi < 4; mi++)
                    acc[mi][1] = mfma16(a[mi][kk], b1[kk], acc[mi][1]);
            __builtin_amdgcn_s_setprio(0);
            BAR;
        }
    }
    VMCNT0;
}

// ======================================================================
// QKV (round-5 proven): 256x256 tile, 8-phase, persistent 256 blocks.
// For wsel==2 (V) the epilogue writes V^T via an LDS transpose bounce.
// ======================================================================
__device__ __forceinline__ void stg_half(const u16* __restrict__ gbase,
                                         u16* unit, int tid) {
#pragma unroll
    for (int i = 0; i < 2; i++) {
        int D = (i * 512 + tid) * 16;
        int r = D >> 7, w = D & 127;
        int gcol = (w ^ ((r & 7) << 4)) >> 1;
        gl_lds16(gbase + (size_t)r * DIN + gcol,
                 unit + (i * 512 + (tid >> 6) * 64) * 8);
    }
}

__device__ __forceinline__ void rdA8(const u16* unit, int mh, int l15, int l4,
                                     int sw, bf16x8 a[4][2]) {
    const char* u = (const char*)unit;
#pragma unroll
    for (int mi = 0; mi < 4; mi++)
#pragma unroll
        for (int kk = 0; kk < 2; kk++)
            a[mi][kk] = *(const bf16x8*)(u + (mh * 64 + mi * 16 + l15) * 128 +
                                         ((kk * 64 + l4 * 16) ^ sw));
}

__device__ __forceinline__ void rdB8(const u16* unit, int wn1, int nh, int l15,
                                     int l4, int sw, bf16x8 b[2][2]) {
    const char* u = (const char*)unit;
#pragma unroll
    for (int ni = 0; ni < 2; ni++)
#pragma unroll
        for (int kk = 0; kk < 2; kk++)
            b[ni][kk] = *(const bf16x8*)(u + (wn1 * 64 + nh * 32 + ni * 16 + l15) * 128 +
                                         ((kk * 64 + l4 * 16) ^ sw));
}

#define QUAD(MH, NH)                                                         \
    __builtin_amdgcn_s_setprio(1);                                           \
    _Pragma("unroll") for (int kk = 0; kk < 2; kk++)                         \
    _Pragma("unroll") for (int mi = 0; mi < 4; mi++)                         \
    _Pragma("unroll") for (int ni = 0; ni < 2; ni++)                         \
        acc[(MH)*4 + mi][(NH)*2 + ni] =                                      \
            mfma16(a[mi][kk], bb[NH][ni][kk], acc[(MH)*4 + mi][(NH)*2 + ni]);\
    __builtin_amdgcn_s_setprio(0);

__global__ __launch_bounds__(512) void qkv_gemm256(const u16* __restrict__ xb,
                                                   const u16* __restrict__ wb,
                                                   u16* __restrict__ qkv,
                                                   u16* __restrict__ vt) {
    extern __shared__ __align__(16) u16 lds[];
    const int tid = threadIdx.x, lane = tid & 63, wid = tid >> 6;
    const int wm = wid >> 2, wn = wid & 3, bh = wn >> 1, wn1 = wn & 1;
    const int l15 = lane & 15, l4 = lane >> 4;
    const int sw = (l15 & 7) << 4;

    u16* A00 = lds;              u16* A01 = lds + 8192;
    u16* A10 = lds + 16384;      u16* A11 = lds + 24576;
    u16* B00 = lds + 32768;      u16* B01 = lds + 40960;
    u16* B10 = lds + 49152;      u16* B11 = lds + 57344;
    u16* Ar0 = lds + wm * 8192;
    u16* Ar1 = lds + 16384 + wm * 8192;
    u16* Br0 = lds + 32768 + bh * 8192;
    u16* Br1 = lds + 49152 + bh * 8192;

    for (int tile = blockIdx.x; tile < 384; tile += 256) {
        const int wg = (tile & 7) * 48 + (tile >> 3);  // round-5 XCD swizzle
        const int mt = wg & 31, nt = wg >> 5;
        const int m0 = mt * 256, n0 = nt * 256;
        const u16* Ag = xb + (size_t)m0 * DIN;
        const u16* Bg = wb + (size_t)n0 * DIN;
        f32x4 acc[8][4] = {};
        bf16x8 a[4][2], bb[2][2][2];

        stg_half(Bg,                          B00, tid);
        stg_half(Bg + (size_t)128 * DIN,      B01, tid);
        stg_half(Ag,                          A00, tid);
        stg_half(Ag + (size_t)128 * DIN,      A01, tid);
        stg_half(Bg + 64,                     B10, tid);
        stg_half(Bg + (size_t)128 * DIN + 64, B11, tid);
        VMCNT4; BAR;

        for (int i = 0; i < 8; i++) {
            const int t1k = (2 * i + 1) * 64;
            const int k2 = ((2 * i + 2 < 16) ? 2 * i + 2 : 15) * 64;
            const int k3 = ((2 * i + 3 < 16) ? 2 * i + 3 : 15) * 64;
            rdA8(Ar0, 0, l15, l4, sw, a);
            rdB8(Br0, wn1, 0, l15, l4, sw, bb[0]);
            stg_half(Ag + t1k, A10, tid);
            BAR; QUAD(0, 0); BAR;
            rdB8(Br0, wn1, 1, l15, l4, sw, bb[1]);
            stg_half(Ag + (size_t)128 * DIN + t1k, A11, tid);
            BAR; QUAD(0, 1); BAR;
            rdA8(Ar0, 1, l15, l4, sw, a);
            stg_half(Bg + k2, B00, tid);
            BAR; QUAD(1, 0); BAR;
            stg_half(Bg + (size_t)128 * DIN + k2, B01, tid);
            VMCNT4; BAR; QUAD(1, 1); BAR;
            rdA8(Ar1, 0, l15, l4, sw, a);
            rdB8(Br1, wn1, 0, l15, l4, sw, bb[0]);
            stg_half(Ag + k2, A00, tid);
            BAR; QUAD(0, 0); BAR;
            rdB8(Br1, wn1, 1, l15, l4, sw, bb[1]);
            stg_half(Ag + (size_t)128 * DIN + k2, A01, tid);
            BAR; QUAD(0, 1); BAR;
            rdA8(Ar1, 1, l15, l4, sw, a);
            stg_half(Bg + k3, B10, tid);
            BAR; QUAD(1, 0); BAR;
            stg_half(Bg + (size_t)128 * DIN + k3, B11, tid);
            VMCNT4; BAR; QUAD(1, 1); BAR;
        }
        VMCNT0;

        const int wsel = n0 >> 10, c0 = n0 & 1023;
        if (wsel < 2) {
            // Q / K: round-5 proven scalar epilogue
            u16* Op = qkv + (size_t)wsel * ((size_t)BATCH * SEQ * DOUT);
#pragma unroll
            for (int ai = 0; ai < 8; ai++)
#pragma unroll
                for (int bj = 0; bj < 4; bj++)
#pragma unroll
                    for (int rr = 0; rr < 4; rr++) {
                        int row = m0 + wm * 128 + ai * 16 + l4 * 4 + rr;
                        int col = c0 + wn * 64 + bj * 16 + l15;
                        Op[(size_t)row * DOUT + col] = f2bf(acc[ai][bj][rr]);
                    }
        } else {
            // V: transpose 256x256 tile through LDS, store V^T coalesced
            BAR;  // all waves' gl_lds drained (each did VMCNT0)
#pragma unroll
            for (int ai = 0; ai < 8; ai++)
#pragma unroll
                for (int bj = 0; bj < 4; bj++) {
                    int dloc = wn * 64 + bj * 16 + l15;
                    int sloc = wm * 128 + ai * 16 + l4 * 4;
                    int byte = (dloc * 512 + sloc * 2) ^ ((dloc & 7) << 4);
                    uint2 o;
                    o.x = (unsigned)f2bf(acc[ai][bj][0]) |
                          ((unsigned)f2bf(acc[ai][bj][1]) << 16);
                    o.y = (unsigned)f2bf(acc[ai][bj][2]) |
                          ((unsigned)f2bf(acc[ai][bj][3]) << 16);
                    *(uint2*)((char*)lds + byte) = o;
                }
            BAR;
            const int batch = m0 >> 11, s0 = m0 & 2047;
            u16* Vt = vt + (size_t)batch * DOUT * SEQ;
#pragma unroll
            for (int i = 0; i < 16; i++) {
                int e = (i * 512 + tid) * 16;
                int dloc = e >> 9, sb = e & 511;
                int byte = e ^ ((dloc & 7) << 4);
                uint4 v = *(const uint4*)((char*)lds + byte);
                *(uint4*)&Vt[(size_t)(c0 + dloc) * SEQ + s0 + (sb >> 1)] = v;
            }
            LGKM0; BAR;  // transpose reads done before next tile stages
        }
    }
}

// ---------------- QK^T: G64 triangular, 544 blocks @ 2/CU ------------------
__global__ __launch_bounds__(512) void qk_g64(const u16* __restrict__ qg,
                                              const u16* __restrict__ kg,
                                              u16* __restrict__ sg) {
    extern __shared__ __align__(16) u16 lds[];
    const int bxx = blockIdx.x, batch = blockIdx.y;
    int mt = 0, base = 0;
#pragma unroll 16
    for (int m = 0; m < 16; m++) {
        int c = m + 1;
        if (bxx < base + c) { mt = m; break; }
        base += c;
    }
    const int nt = bxx - base;
    const int m0 = mt * 128, n0 = nt * 128;
    const int tid = threadIdx.x, lane = tid & 63;
    const int wm = (tid >> 6) >> 2, wn = (tid >> 6) & 3;
    const int l15 = lane & 15, l4 = lane >> 4;
    const size_t bo = (size_t)batch * SEQ * DOUT;

    f32x4 acc[4][2] = {};
    g64_body(lds, qg + bo + (size_t)m0 * DOUT, DOUT,
             kg + bo + (size_t)n0 * DOUT, DOUT, 16,
             wm, wn, l15, l4, tid, acc);

    u16* Sp = sg + (size_t)batch * SEQ * SEQ;
#pragma unroll
    for (int ai = 0; ai < 4; ai++)
#pragma unroll
        for (int bj = 0; bj < 2; bj++)
#pragma unroll
            for (int rr = 0; rr < 4; rr++) {
                int q = m0 + wm * 64 + ai * 16 + l4 * 4 + rr;
                int kc = n0 + wn * 32 + bj * 16 + l15;
                Sp[(size_t)q * SEQ + kc] =
                    (kc <= q) ? f2bf(acc[ai][bj][rr] * SCALE) : (u16)0xFF80;
            }
}

// ---------------- PV: G64 paired (mt=j & mt=15-j), uniform 34 steps --------
__global__ __launch_bounds__(512) void pv_g64(const u16* __restrict__ pg,
                                              const u16* __restrict__ vtg,
                                              float* __restrict__ og) {
    extern __shared__ __align__(16) u16 lds[];
    const int pr = blockIdx.x;             // 0..7
    const int n0 = blockIdx.y * 128, batch = blockIdx.z;
    const int tid = threadIdx.x, lane = tid & 63;
    const int wm = (tid >> 6) >> 2, wn = (tid >> 6) & 3;
    const int l15 = lane & 15, l4 = lane >> 4;
    const u16* Pb = pg + (size_t)batch * SEQ * SEQ;
    const u16* Vb = vtg + (size_t)batch * DOUT * SEQ + (size_t)n0 * SEQ;
    float* Ob = og + (size_t)batch * SEQ * DOUT;

#pragma unroll
    for (int half = 0; half < 2; half++) {
        const int mt = half ? (15 - pr) : pr;
        const int m0 = mt * 128;
        f32x4 acc[4][2] = {};
        g64_body(lds, Pb + (size_t)m0 * SEQ, SEQ, Vb, SEQ, (mt + 1) * 2,
                 wm, wn, l15, l4, tid, acc);
#pragma unroll
        for (int ai = 0; ai < 4; ai++)
#pragma unroll
            for (int bj = 0; bj < 2; bj++)
#pragma unroll
                for (int rr = 0; rr < 4; rr++) {
                    int q = m0 + wm * 64 + ai * 16 + l4 * 4 + rr;
                    int d = n0 + wn * 32 + bj * 16 + l15;
                    Ob[(size_t)q * DOUT + d] = acc[ai][bj][rr];
                }
    }
}

// ---------------- row softmax in place: one wave per row -------------------
__global__ __launch_bounds__(256) void softmax_rows(u16* __restrict__ sg) {
    const int row = blockIdx.x * 4 + (threadIdx.x >> 6);
    const int lane = threadIdx.x & 63;
    const int b = row >> 11, q = row & 2047;
    u16* srow = sg + (size_t)b * SEQ * SEQ + (size_t)q * SEQ;
    const int kend = ((q >> 7) + 1) << 7;
    float v[4][8];
    float m = -__builtin_inff();
#pragma unroll
    for (int c = 0; c < 4; c++) {
        int k = c * 512 + lane * 8;
        if (k < kend) {
            uint4 x = *(const uint4*)&srow[k];
            unsigned w0 = x.x, w1 = x.y, w2 = x.z, w3 = x.w;
            v[c][0] = __uint_as_float(w0 << 16); v[c][1] = __uint_as_float(w0 & 0xffff0000u);
            v[c][2] = __uint_as_float(w1 << 16); v[c][3] = __uint_as_float(w1 & 0xffff0000u);
            v[c][4] = __uint_as_float(w2 << 16); v[c][5] = __uint_as_float(w2 & 0xffff0000u);
            v[c][6] = __uint_as_float(w3 << 16); v[c][7] = __uint_as_float(w3 & 0xffff0000u);
        } else {
#pragma unroll
            for (int j = 0; j < 8; j++) v[c][j] = -__builtin_inff();
        }
#pragma unroll
        for (int j = 0; j < 8; j++) m = fmaxf(m, v[c][j]);
    }
#pragma unroll
    for (int off = 32; off >= 1; off >>= 1) m = fmaxf(m, __shfl_xor(m, off));
    float s = 0.f;
#pragma unroll
    for (int c = 0; c < 4; c++)
#pragma unroll
        for (int j = 0; j < 8; j++) { v[c][j] = __expf(v[c][j] - m); s += v[c][j]; }
#pragma unroll
    for (int off = 32; off >= 1; off >>= 1) s += __shfl_xor(s, off);
    float inv = 1.f / s;
#pragma unroll
    for (int c = 0; c < 4; c++) {
        int k = c * 512 + lane * 8;
        if (k < kend) {
            uint4 o;
            o.x = (unsigned)f2bf(v[c][0] * inv) | ((unsigned)f2bf(v[c][1] * inv) << 16);
            o.y = (unsigned)f2bf(v[c][2] * inv) | ((unsigned)f2bf(v[c][3] * inv) << 16);
            o.z = (unsigned)f2bf(v[c][4] * inv) | ((unsigned)f2bf(v[c][5] * inv) << 16);
            o.w = (unsigned)f2bf(v[c][6] * inv) | ((unsigned)f2bf(v[c][7] * inv) << 16);
            *(uint4*)&srow[k] = o;
        }
    }
}

extern "C" void kernel_launch(void* const* d_in, const int* in_sizes, int n_in,
                              void* d_out, int out_size, void* d_ws, size_t ws_size,
                              hipStream_t stream) {
    const float* x  = (const float*)d_in[0];
    const float* wq = (const float*)d_in[1];
    const float* wk = (const float*)d_in[2];
    const float* wv = (const float*)d_in[3];
    float* out = (float*)d_out;

    const size_t NX  = (size_t)BATCH * SEQ * DIN;  // 8M elems
    const size_t NWT = (size_t)DOUT * DIN;         // 1M elems
    u16* xb  = (u16*)d_ws;            // 16 MB
    u16* wb  = xb + NX;               // 6 MB (wq|wk|wv = Wcat[3072][1024])
    u16* qkv = wb + 3 * NWT;          // 48 MB (q,k; v region unused)
    u16* vt  = qkv + 3 * NX;          // 16 MB (V^T, written by qkv epilogue)
    u16* sb  = vt + NX;               // 33.5 MB scores/probs (bf16, in-place)

    cvt_all<<<(NX + 3 * NWT) / 8 / 256, 256, 0, stream>>>(x, wq, wk, wv, xb);

    (void)hipFuncSetAttribute((const void*)qkv_gemm256,
                              hipFuncAttributeMaxDynamicSharedMemorySize, 131072);
    (void)hipFuncSetAttribute((const void*)qk_g64,
                              hipFuncAttributeMaxDynamicSharedMemorySize, 65536);
    (void)hipFuncSetAttribute((const void*)pv_g64,
                              hipFuncAttributeMaxDynamicSharedMemorySize, 65536);

    qkv_gemm256<<<dim3(256), dim3(512), 131072, stream>>>(xb, wb, qkv, vt);

    qk_g64<<<dim3(136, BATCH), dim3(512), 65536, stream>>>(qkv, qkv + NX, sb);

    softmax_rows<<<(BATCH * SEQ) / 4, 256, 0, stream>>>(sb);

    pv_g64<<<dim3(8, 8, 4), dim3(512), 65536, stream>>>(sb, vt, out);
}

// Round 9
// 167.852 us; speedup vs baseline: 1.1012x; 1.1012x over previous
//
#include <hip/hip_runtime.h>
#include <hip/hip_bf16.h>
#include <cstdint>

#define BATCH 4
#define SEQ   2048
#define DIN   1024
#define DOUT  1024
#define SCALE 0.03125f   // 1/sqrt(1024)

typedef unsigned short u16;
typedef float  f32x4  __attribute__((ext_vector_type(4)));
typedef __bf16 bf16x8 __attribute__((ext_vector_type(8)));

__device__ __forceinline__ u16 f2bf(float f) {
    unsigned u = __float_as_uint(f);
    unsigned r = 0x7fffu + ((u >> 16) & 1u);
    return (u16)((u + r) >> 16);
}

__device__ __forceinline__ f32x4 mfma16(bf16x8 a, bf16x8 b, f32x4 c) {
    return __builtin_amdgcn_mfma_f32_16x16x32_bf16(a, b, c, 0, 0, 0);
}

__device__ __forceinline__ void gl_lds16(const u16* g, u16* l) {
    __builtin_amdgcn_global_load_lds(
        (const __attribute__((address_space(1))) unsigned int*)g,
        (__attribute__((address_space(3))) unsigned int*)l, 16, 0, 0);
}

#define BAR    asm volatile("s_barrier" ::: "memory")
#define VMCNT4 asm volatile("s_waitcnt vmcnt(4)" ::: "memory")
#define VMCNT0 asm volatile("s_waitcnt vmcnt(0)" ::: "memory")
#define LGKM0  asm volatile("s_waitcnt lgkmcnt(0)" ::: "memory")

// ---------------- fused fp32 -> bf16 conversion (x | wq | wk | wv) ---------
__global__ __launch_bounds__(256) void cvt_all(const float* __restrict__ x,
                                               const float* __restrict__ wq,
                                               const float* __restrict__ wk,
                                               const float* __restrict__ wv,
                                               u16* __restrict__ dst) {
    const size_t NX = (size_t)BATCH * SEQ * DIN;
    size_t e = ((size_t)blockIdx.x * 256 + threadIdx.x) * 8;
    const float* src;
    size_t off;
    if (e < NX) { src = x; off = e; }
    else {
        size_t r = e - NX;
        int w = (int)(r >> 20);
        src = (w == 0) ? wq : (w == 1) ? wk : wv;
        off = r & ((1u << 20) - 1);
    }
    f32x4 a = *(const f32x4*)(src + off);
    f32x4 b = *(const f32x4*)(src + off + 4);
    uint4 o;
    o.x = (unsigned)f2bf(a[0]) | ((unsigned)f2bf(a[1]) << 16);
    o.y = (unsigned)f2bf(a[2]) | ((unsigned)f2bf(a[3]) << 16);
    o.z = (unsigned)f2bf(b[0]) | ((unsigned)f2bf(b[1]) << 16);
    o.w = (unsigned)f2bf(b[2]) | ((unsigned)f2bf(b[3]) << 16);
    *(uint4*)(dst + e) = o;
}

// ======================================================================
// Staging: 128-row x 64-col bf16 unit (16KB), linear rows, row-XOR
// swizzle (byte ^= (row&7)<<4) applied inverse on the global source.
// ======================================================================
__device__ __forceinline__ void stg128(const u16* __restrict__ g, int ld,
                                       u16* unit, int tid) {
#pragma unroll
    for (int i = 0; i < 2; i++) {
        int D = (i * 512 + tid) * 16;
        int r = D >> 7, w = D & 127;
        int gcol = (w ^ ((r & 7) << 4)) >> 1;
        gl_lds16(g + (size_t)r * ld + gcol, unit + (i * 512 + (tid >> 6) * 64) * 8);
    }
}

__device__ __forceinline__ void rd4(const u16* unit, int rowbase, int l15, int l4,
                                    bf16x8 f[4][2]) {
    const char* u = (const char*)unit;
#pragma unroll
    for (int i = 0; i < 4; i++) {
        int row = rowbase + i * 16 + l15;
#pragma unroll
        for (int kk = 0; kk < 2; kk++)
            f[i][kk] = *(const bf16x8*)(u + row * 128 +
                                        ((kk * 64 + l4 * 16) ^ ((row & 7) << 4)));
    }
}

__device__ __forceinline__ void rd2k(const u16* unit, int row0, int l15, int l4,
                                     bf16x8 f[2]) {
    const char* u = (const char*)unit;
    int row = row0 + l15;
#pragma unroll
    for (int kk = 0; kk < 2; kk++)
        f[kk] = *(const bf16x8*)(u + row * 128 +
                                 ((kk * 64 + l4 * 16) ^ ((row & 7) << 4)));
}

// ======================================================================
// G64: 128x128 tile, BK=64, 8 waves (2M x 4N), per-wave 64x32, 64KB LDS.
// ======================================================================
__device__ __forceinline__ void g64_body(u16* lds, const u16* __restrict__ Ag,
                                         int lda, const u16* __restrict__ Bg,
                                         int ldb, int nkt, int wm, int wn,
                                         int l15, int l4, int tid,
                                         f32x4 acc[4][2]) {
    bf16x8 a[4][2], b0[2], b1[2];
    u16* A0 = lds;          u16* B0 = lds + 8192;
    u16* A1 = lds + 16384;  u16* B1 = lds + 24576;
    stg128(Ag, lda, A0, tid);      stg128(Bg, ldb, B0, tid);
    stg128(Ag + 64, lda, A1, tid); stg128(Bg + 64, ldb, B1, tid);
    VMCNT4; BAR;
    for (int t = 0; t < nkt; t += 2) {
        {
            const int k2 = ((t + 2 < nkt) ? t + 2 : nkt - 1) * 64;
            rd4(A0, wm * 64, l15, l4, a);
            rd2k(B0, wn * 32, l15, l4, b0);
            rd2k(B0, wn * 32 + 16, l15, l4, b1);
            BAR;
            __builtin_amdgcn_s_setprio(1);
#pragma unroll
            for (int kk = 0; kk < 2; kk++)
#pragma unroll
                for (int mi = 0; mi < 4; mi++)
                    acc[mi][0] = mfma16(a[mi][kk], b0[kk], acc[mi][0]);
            __builtin_amdgcn_s_setprio(0);
            LGKM0; BAR;
            stg128(Ag + k2, lda, A0, tid);
            stg128(Bg + k2, ldb, B0, tid);
            VMCNT4; BAR;
            __builtin_amdgcn_s_setprio(1);
#pragma unroll
            for (int kk = 0; kk < 2; kk++)
#pragma unroll
                for (int mi = 0; mi < 4; mi++)
                    acc[mi][1] = mfma16(a[mi][kk], b1[kk], acc[mi][1]);
            __builtin_amdgcn_s_setprio(0);
            BAR;
        }
        {
            const int k3 = ((t + 3 < nkt) ? t + 3 : nkt - 1) * 64;
            rd4(A1, wm * 64, l15, l4, a);
            rd2k(B1, wn * 32, l15, l4, b0);
            rd2k(B1, wn * 32 + 16, l15, l4, b1);
            BAR;
            __builtin_amdgcn_s_setprio(1);
#pragma unroll
            for (int kk = 0; kk < 2; kk++)
#pragma unroll
                for (int mi = 0; mi < 4; mi++)
                    acc[mi][0] = mfma16(a[mi][kk], b0[kk], acc[mi][0]);
            __builtin_amdgcn_s_setprio(0);
            LGKM0; BAR;
            stg128(Ag + k3, lda, A1, tid);
            stg128(Bg + k3, ldb, B1, tid);
            VMCNT4; BAR;
            __builtin_amdgcn_s_setprio(1);
#pragma unroll
            for (int kk = 0; kk < 2; kk++)
#pragma unroll
                for (int mi = 0; mi < 4; mi++)
                    acc[mi][1] = mfma16(a[mi][kk], b1[kk], acc[mi][1]);
            __builtin_amdgcn_s_setprio(0);
            BAR;
        }
    }
    VMCNT0;
}

// ======================================================================
// QKV: round-5 exact. 256x256 tile, BK=64, 8 waves, 8-phase schedule,
// vmcnt(4) at ph3/ph7, persistent 256 blocks over 384 tiles.
// ======================================================================
__device__ __forceinline__ void stg_half(const u16* __restrict__ gbase,
                                         u16* unit, int tid) {
#pragma unroll
    for (int i = 0; i < 2; i++) {
        int D = (i * 512 + tid) * 16;
        int r = D >> 7, w = D & 127;
        int gcol = (w ^ ((r & 7) << 4)) >> 1;
        gl_lds16(gbase + (size_t)r * DIN + gcol,
                 unit + (i * 512 + (tid >> 6) * 64) * 8);
    }
}

__device__ __forceinline__ void rdA8(const u16* unit, int mh, int l15, int l4,
                                     int sw, bf16x8 a[4][2]) {
    const char* u = (const char*)unit;
#pragma unroll
    for (int mi = 0; mi < 4; mi++)
#pragma unroll
        for (int kk = 0; kk < 2; kk++)
            a[mi][kk] = *(const bf16x8*)(u + (mh * 64 + mi * 16 + l15) * 128 +
                                         ((kk * 64 + l4 * 16) ^ sw));
}

__device__ __forceinline__ void rdB8(const u16* unit, int wn1, int nh, int l15,
                                     int l4, int sw, bf16x8 b[2][2]) {
    const char* u = (const char*)unit;
#pragma unroll
    for (int ni = 0; ni < 2; ni++)
#pragma unroll
        for (int kk = 0; kk < 2; kk++)
            b[ni][kk] = *(const bf16x8*)(u + (wn1 * 64 + nh * 32 + ni * 16 + l15) * 128 +
                                         ((kk * 64 + l4 * 16) ^ sw));
}

#define QUAD(MH, NH)                                                         \
    __builtin_amdgcn_s_setprio(1);                                           \
    _Pragma("unroll") for (int kk = 0; kk < 2; kk++)                         \
    _Pragma("unroll") for (int mi = 0; mi < 4; mi++)                         \
    _Pragma("unroll") for (int ni = 0; ni < 2; ni++)                         \
        acc[(MH)*4 + mi][(NH)*2 + ni] =                                      \
            mfma16(a[mi][kk], bb[NH][ni][kk], acc[(MH)*4 + mi][(NH)*2 + ni]);\
    __builtin_amdgcn_s_setprio(0);

__global__ __launch_bounds__(512) void qkv_gemm256(const u16* __restrict__ xb,
                                                   const u16* __restrict__ wb,
                                                   u16* __restrict__ qkv) {
    extern __shared__ __align__(16) u16 lds[];
    const int tid = threadIdx.x, lane = tid & 63, wid = tid >> 6;
    const int wm = wid >> 2, wn = wid & 3, bh = wn >> 1, wn1 = wn & 1;
    const int l15 = lane & 15, l4 = lane >> 4;
    const int sw = (l15 & 7) << 4;

    u16* A00 = lds;              u16* A01 = lds + 8192;
    u16* A10 = lds + 16384;      u16* A11 = lds + 24576;
    u16* B00 = lds + 32768;      u16* B01 = lds + 40960;
    u16* B10 = lds + 49152;      u16* B11 = lds + 57344;
    u16* Ar0 = lds + wm * 8192;
    u16* Ar1 = lds + 16384 + wm * 8192;
    u16* Br0 = lds + 32768 + bh * 8192;
    u16* Br1 = lds + 49152 + bh * 8192;

    for (int tile = blockIdx.x; tile < 384; tile += 256) {
        const int wg = (tile & 7) * 48 + (tile >> 3);  // bijective XCD swizzle
        const int mt = wg & 31, nt = wg >> 5;
        const int m0 = mt * 256, n0 = nt * 256;
        const u16* Ag = xb + (size_t)m0 * DIN;
        const u16* Bg = wb + (size_t)n0 * DIN;
        f32x4 acc[8][4] = {};
        bf16x8 a[4][2], bb[2][2][2];

        stg_half(Bg,                          B00, tid);
        stg_half(Bg + (size_t)128 * DIN,      B01, tid);
        stg_half(Ag,                          A00, tid);
        stg_half(Ag + (size_t)128 * DIN,      A01, tid);
        stg_half(Bg + 64,                     B10, tid);
        stg_half(Bg + (size_t)128 * DIN + 64, B11, tid);
        VMCNT4; BAR;

        for (int i = 0; i < 8; i++) {
            const int t1k = (2 * i + 1) * 64;
            const int k2 = ((2 * i + 2 < 16) ? 2 * i + 2 : 15) * 64;
            const int k3 = ((2 * i + 3 < 16) ? 2 * i + 3 : 15) * 64;
            rdA8(Ar0, 0, l15, l4, sw, a);
            rdB8(Br0, wn1, 0, l15, l4, sw, bb[0]);
            stg_half(Ag + t1k, A10, tid);
            BAR; QUAD(0, 0); BAR;
            rdB8(Br0, wn1, 1, l15, l4, sw, bb[1]);
            stg_half(Ag + (size_t)128 * DIN + t1k, A11, tid);
            BAR; QUAD(0, 1); BAR;
            rdA8(Ar0, 1, l15, l4, sw, a);
            stg_half(Bg + k2, B00, tid);
            BAR; QUAD(1, 0); BAR;
            stg_half(Bg + (size_t)128 * DIN + k2, B01, tid);
            VMCNT4; BAR; QUAD(1, 1); BAR;
            rdA8(Ar1, 0, l15, l4, sw, a);
            rdB8(Br1, wn1, 0, l15, l4, sw, bb[0]);
            stg_half(Ag + k2, A00, tid);
            BAR; QUAD(0, 0); BAR;
            rdB8(Br1, wn1, 1, l15, l4, sw, bb[1]);
            stg_half(Ag + (size_t)128 * DIN + k2, A01, tid);
            BAR; QUAD(0, 1); BAR;
            rdA8(Ar1, 1, l15, l4, sw, a);
            stg_half(Bg + k3, B10, tid);
            BAR; QUAD(1, 0); BAR;
            stg_half(Bg + (size_t)128 * DIN + k3, B11, tid);
            VMCNT4; BAR; QUAD(1, 1); BAR;
        }
        VMCNT0;

        const int wsel = n0 >> 10, c0 = n0 & 1023;
        u16* Op = qkv + (size_t)wsel * ((size_t)BATCH * SEQ * DOUT);
#pragma unroll
        for (int ai = 0; ai < 8; ai++)
#pragma unroll
            for (int bj = 0; bj < 4; bj++)
#pragma unroll
                for (int rr = 0; rr < 4; rr++) {
                    int row = m0 + wm * 128 + ai * 16 + l4 * 4 + rr;
                    int col = c0 + wn * 64 + bj * 16 + l15;
                    Op[(size_t)row * DOUT + col] = f2bf(acc[ai][bj][rr]);
                }
    }
}

// ---------------- V transpose: v[b][s][d] -> vt[b][d][s] -------------------
__global__ __launch_bounds__(256) void vtrans(const u16* __restrict__ v,
                                              u16* __restrict__ vt) {
    __shared__ __align__(16) u16 t[64][80];
    const int s0 = blockIdx.x * 64, d0 = blockIdx.y * 64;
    const size_t bo = (size_t)blockIdx.z * SEQ * DOUT;
    const int tid = threadIdx.x;
#pragma unroll
    for (int i = 0; i < 2; i++) {
        int e = (tid + i * 256) * 8;
        int r = e >> 6, c = e & 63;
        *(uint4*)&t[r][c] = *(const uint4*)&v[bo + (size_t)(s0 + r) * DOUT + d0 + c];
    }
    __syncthreads();
#pragma unroll
    for (int i = 0; i < 2; i++) {
        int e = (tid + i * 256) * 8;
        int rd = e >> 6, cs = e & 63;
        u16 tmp[8];
#pragma unroll
        for (int j = 0; j < 8; j++) tmp[j] = t[cs + j][rd];
        uint4 o;
        o.x = (unsigned)tmp[0] | ((unsigned)tmp[1] << 16);
        o.y = (unsigned)tmp[2] | ((unsigned)tmp[3] << 16);
        o.z = (unsigned)tmp[4] | ((unsigned)tmp[5] << 16);
        o.w = (unsigned)tmp[6] | ((unsigned)tmp[7] << 16);
        *(uint4*)&vt[(size_t)blockIdx.z * DOUT * SEQ + (size_t)(d0 + rd) * SEQ + s0 + cs] = o;
    }
}

// ---------------- QK^T: G64 triangular, 544 blocks @ 2/CU ------------------
__global__ __launch_bounds__(512) void qk_g64(const u16* __restrict__ qg,
                                              const u16* __restrict__ kg,
                                              u16* __restrict__ sg) {
    extern __shared__ __align__(16) u16 lds[];
    const int bxx = blockIdx.x, batch = blockIdx.y;
    int mt = 0, base = 0;
#pragma unroll 16
    for (int m = 0; m < 16; m++) {
        int c = m + 1;
        if (bxx < base + c) { mt = m; break; }
        base += c;
    }
    const int nt = bxx - base;
    const int m0 = mt * 128, n0 = nt * 128;
    const int tid = threadIdx.x, lane = tid & 63;
    const int wm = (tid >> 6) >> 2, wn = (tid >> 6) & 3;
    const int l15 = lane & 15, l4 = lane >> 4;
    const size_t bo = (size_t)batch * SEQ * DOUT;

    f32x4 acc[4][2] = {};
    g64_body(lds, qg + bo + (size_t)m0 * DOUT, DOUT,
             kg + bo + (size_t)n0 * DOUT, DOUT, 16,
             wm, wn, l15, l4, tid, acc);

    u16* Sp = sg + (size_t)batch * SEQ * SEQ;
#pragma unroll
    for (int ai = 0; ai < 4; ai++)
#pragma unroll
        for (int bj = 0; bj < 2; bj++)
#pragma unroll
            for (int rr = 0; rr < 4; rr++) {
                int q = m0 + wm * 64 + ai * 16 + l4 * 4 + rr;
                int kc = n0 + wn * 32 + bj * 16 + l15;
                Sp[(size_t)q * SEQ + kc] =
                    (kc <= q) ? f2bf(acc[ai][bj][rr] * SCALE) : (u16)0xFF80;
            }
}

// ---------------- PV: G64 paired (mt=j & mt=15-j), uniform 34 steps --------
__global__ __launch_bounds__(512) void pv_g64(const u16* __restrict__ pg,
                                              const u16* __restrict__ vtg,
                                              float* __restrict__ og) {
    extern __shared__ __align__(16) u16 lds[];
    const int pr = blockIdx.x;             // 0..7
    const int n0 = blockIdx.y * 128, batch = blockIdx.z;
    const int tid = threadIdx.x, lane = tid & 63;
    const int wm = (tid >> 6) >> 2, wn = (tid >> 6) & 3;
    const int l15 = lane & 15, l4 = lane >> 4;
    const u16* Pb = pg + (size_t)batch * SEQ * SEQ;
    const u16* Vb = vtg + (size_t)batch * DOUT * SEQ + (size_t)n0 * SEQ;
    float* Ob = og + (size_t)batch * SEQ * DOUT;

#pragma unroll
    for (int half = 0; half < 2; half++) {
        const int mt = half ? (15 - pr) : pr;
        const int m0 = mt * 128;
        f32x4 acc[4][2] = {};
        g64_body(lds, Pb + (size_t)m0 * SEQ, SEQ, Vb, SEQ, (mt + 1) * 2,
                 wm, wn, l15, l4, tid, acc);
#pragma unroll
        for (int ai = 0; ai < 4; ai++)
#pragma unroll
            for (int bj = 0; bj < 2; bj++)
#pragma unroll
                for (int rr = 0; rr < 4; rr++) {
                    int q = m0 + wm * 64 + ai * 16 + l4 * 4 + rr;
                    int d = n0 + wn * 32 + bj * 16 + l15;
                    Ob[(size_t)q * DOUT + d] = acc[ai][bj][rr];
                }
    }
}

// ---------------- row softmax in place: one wave per row -------------------
__global__ __launch_bounds__(256) void softmax_rows(u16* __restrict__ sg) {
    const int row = blockIdx.x * 4 + (threadIdx.x >> 6);
    const int lane = threadIdx.x & 63;
    const int b = row >> 11, q = row & 2047;
    u16* srow = sg + (size_t)b * SEQ * SEQ + (size_t)q * SEQ;
    const int kend = ((q >> 7) + 1) << 7;
    float v[4][8];
    float m = -__builtin_inff();
#pragma unroll
    for (int c = 0; c < 4; c++) {
        int k = c * 512 + lane * 8;
        if (k < kend) {
            uint4 x = *(const uint4*)&srow[k];
            unsigned w0 = x.x, w1 = x.y, w2 = x.z, w3 = x.w;
            v[c][0] = __uint_as_float(w0 << 16); v[c][1] = __uint_as_float(w0 & 0xffff0000u);
            v[c][2] = __uint_as_float(w1 << 16); v[c][3] = __uint_as_float(w1 & 0xffff0000u);
            v[c][4] = __uint_as_float(w2 << 16); v[c][5] = __uint_as_float(w2 & 0xffff0000u);
            v[c][6] = __uint_as_float(w3 << 16); v[c][7] = __uint_as_float(w3 & 0xffff0000u);
        } else {
#pragma unroll
            for (int j = 0; j < 8; j++) v[c][j] = -__builtin_inff();
        }
#pragma unroll
        for (int j = 0; j < 8; j++) m = fmaxf(m, v[c][j]);
    }
#pragma unroll
    for (int off = 32; off >= 1; off >>= 1) m = fmaxf(m, __shfl_xor(m, off));
    float s = 0.f;
#pragma unroll
    for (int c = 0; c < 4; c++)
#pragma unroll
        for (int j = 0; j < 8; j++) { v[c][j] = __expf(v[c][j] - m); s += v[c][j]; }
#pragma unroll
    for (int off = 32; off >= 1; off >>= 1) s += __shfl_xor(s, off);
    float inv = 1.f / s;
#pragma unroll
    for (int c = 0; c < 4; c++) {
        int k = c * 512 + lane * 8;
        if (k < kend) {
            uint4 o;
            o.x = (unsigned)f2bf(v[c][0] * inv) | ((unsigned)f2bf(v[c][1] * inv) << 16);
            o.y = (unsigned)f2bf(v[c][2] * inv) | ((unsigned)f2bf(v[c][3] * inv) << 16);
            o.z = (unsigned)f2bf(v[c][4] * inv) | ((unsigned)f2bf(v[c][5] * inv) << 16);
            o.w = (unsigned)f2bf(v[c][6] * inv) | ((unsigned)f2bf(v[c][7] * inv) << 16);
            *(uint4*)&srow[k] = o;
        }
    }
}

extern "C" void kernel_launch(void* const* d_in, const int* in_sizes, int n_in,
                              void* d_out, int out_size, void* d_ws, size_t ws_size,
                              hipStream_t stream) {
    const float* x  = (const float*)d_in[0];
    const float* wq = (const float*)d_in[1];
    const float* wk = (const float*)d_in[2];
    const float* wv = (const float*)d_in[3];
    float* out = (float*)d_out;

    const size_t NX  = (size_t)BATCH * SEQ * DIN;  // 8M elems
    const size_t NWT = (size_t)DOUT * DIN;         // 1M elems
    u16* xb  = (u16*)d_ws;            // 16 MB
    u16* wb  = xb + NX;               // 6 MB (wq|wk|wv = Wcat[3072][1024])
    u16* qkv = wb + 3 * NWT;          // 48 MB (q,k,v)
    u16* vt  = qkv + 3 * NX;          // 16 MB
    u16* sb  = vt + NX;               // 33.5 MB scores/probs (bf16, in-place)

    cvt_all<<<(NX + 3 * NWT) / 8 / 256, 256, 0, stream>>>(x, wq, wk, wv, xb);

    (void)hipFuncSetAttribute((const void*)qkv_gemm256,
                              hipFuncAttributeMaxDynamicSharedMemorySize, 131072);
    (void)hipFuncSetAttribute((const void*)qk_g64,
                              hipFuncAttributeMaxDynamicSharedMemorySize, 65536);
    (void)hipFuncSetAttribute((const void*)pv_g64,
                              hipFuncAttributeMaxDynamicSharedMemorySize, 65536);

    qkv_gemm256<<<dim3(256), dim3(512), 131072, stream>>>(xb, wb, qkv);

    vtrans<<<dim3(SEQ / 64, DOUT / 64, BATCH), 256, 0, stream>>>(qkv + 2 * NX, vt);

    qk_g64<<<dim3(136, BATCH), dim3(512), 65536, stream>>>(qkv, qkv + NX, sb);

    softmax_rows<<<(BATCH * SEQ) / 4, 256, 0, stream>>>(sb);

    pv_g64<<<dim3(8, 8, 4), dim3(512), 65536, stream>>>(sb, vt, out);
}